// Round 9
// baseline (416.889 us; speedup 1.0000x reference)
//
#include <hip/hip_runtime.h>
#include <cstdint>
#include <cstddef>

#define NN 10000
#define EE 160000
#define EN_ (EE + NN)
#define MPAD 10112   // 79 * 128
#define MT 79        // M tiles
#define CAP 128      // agg edge-chunk (max deg ~45 -> single chunk)

typedef short s16x8 __attribute__((ext_vector_type(8)));
typedef float f32x4 __attribute__((ext_vector_type(4)));
typedef unsigned short u16;
typedef unsigned char u8;

__device__ __forceinline__ u16 f2bf(float f) {
  uint32_t u = __float_as_uint(f);
  uint32_t r = (u + 0x7fffu + ((u >> 16) & 1u)) >> 16;
  return (u16)r;
}
__device__ __forceinline__ float b2f_lo(uint32_t p) { return __uint_as_float(p << 16); }
__device__ __forceinline__ float b2f_hi(uint32_t p) { return __uint_as_float(p & 0xffff0000u); }
__device__ __forceinline__ float lrelu02(float x) { return x > 0.f ? x : 0.2f * x; }
__device__ __forceinline__ float eluf(float x) { return x > 0.f ? x : (__expf(x) - 1.f); }
__device__ __forceinline__ u8 f2fp8(float v) {
  v = fminf(fmaxf(v, -448.f), 448.f);
  return (u8)(__builtin_amdgcn_cvt_pk_fp8_f32(v, v, 0, false) & 0xff);
}

// ---------------- CSR build ----------------
__global__ void k_count(const int* __restrict__ ei, int* __restrict__ cnt) {
  int e = blockIdx.x * blockDim.x + threadIdx.x;
  if (e >= EN_) return;
  int d = (e < EE) ? ei[EE + e] : (e - EE);
  atomicAdd(&cnt[d], 1);
}

__global__ __launch_bounds__(1024) void k_scan(const int* __restrict__ cnt, int* __restrict__ off) {
  __shared__ int sums[1024];
  int t = threadIdx.x;
  const int per = (NN + 1023) / 1024;  // 10
  int base = t * per;
  int local = 0;
  for (int j = 0; j < per; ++j) {
    int idx = base + j;
    if (idx < NN) local += cnt[idx];
  }
  sums[t] = local;
  __syncthreads();
  for (int s = 1; s < 1024; s <<= 1) {
    int v = (t >= s) ? sums[t - s] : 0;
    __syncthreads();
    sums[t] += v;
    __syncthreads();
  }
  int run = (t == 0) ? 0 : sums[t - 1];
  for (int j = 0; j < per; ++j) {
    int idx = base + j;
    if (idx < NN) { off[idx] = run; run += cnt[idx]; }
  }
  if (t == 1023) off[NN] = EN_;
}

__global__ void k_fill(const int* __restrict__ ei, const int* __restrict__ off,
                       int* __restrict__ cursor, int* __restrict__ csr_src) {
  int e = blockIdx.x * blockDim.x + threadIdx.x;
  if (e >= EN_) return;
  int s, d;
  if (e < EE) { s = ei[e]; d = ei[EE + e]; } else { s = d = e - EE; }
  int p = atomicAdd(&cursor[d], 1);
  csr_src[off[d] + p] = s;
}

// ---------------- mega prep ----------------
// [0,768) transposes | [768,3296) x2b | [3296,3352) bufX pad | [3352,3470) cnt zero
// [3470,3490) fb
#define PREP_BLOCKS 3490
__global__ __launch_bounds__(256) void k_prep(
    const float* __restrict__ x, u16* __restrict__ xb,
    const float* __restrict__ W1, const float* __restrict__ lW1,
    const float* __restrict__ W2, const float* __restrict__ lW2,
    const float* __restrict__ W3, const float* __restrict__ lW3,
    u16* __restrict__ wtc1, u16* __restrict__ wtc2, u16* __restrict__ wtc3,
    const float* __restrict__ lb1, const float* __restrict__ lb2,
    const float* __restrict__ lb3, float* __restrict__ fb,
    u16* __restrict__ bufX, int* __restrict__ cnt) {
  int b = blockIdx.x, t = threadIdx.x;
  if (b < 768) {
    const float* W; u16* Bt; int K, N, Kpad, nb, kb;
    if (b < 16)       { W = W1;  Bt = wtc1;                       K = 50;   N = 1024; Kpad = 64;   nb = b;      kb = 0; }
    else if (b < 32)  { W = lW1; Bt = wtc1 + (size_t)1024 * 64;   K = 50;   N = 1024; Kpad = 64;   nb = b - 16; kb = 0; }
    else if (b < 288) { int r = b - 32;  W = W2;  Bt = wtc2;                         K = 1024; N = 1024; Kpad = 1024; nb = r & 15; kb = r >> 4; }
    else if (b < 544) { int r = b - 288; W = lW2; Bt = wtc2 + (size_t)1024 * 1024;   K = 1024; N = 1024; Kpad = 1024; nb = r & 15; kb = r >> 4; }
    else if (b < 736) { int r = b - 544; W = W3;  Bt = wtc3;                         K = 1024; N = 726;  Kpad = 1024; nb = r % 12; kb = r / 12; }
    else              { int r = b - 736; W = lW3; Bt = wtc3 + (size_t)768 * 1024;    K = 1024; N = 121;  Kpad = 1024; nb = r & 1;  kb = r >> 1; }
    __shared__ float tile[64][65];
    int kbase = kb * 64, nbase = nb * 64;
    int nl = t & 63, kl0 = t >> 6;
#pragma unroll
    for (int j = 0; j < 16; ++j) {
      int k = kbase + kl0 + j * 4, n = nbase + nl;
      tile[kl0 + j * 4][nl] = (k < K && n < N) ? W[(size_t)k * N + n] : 0.f;
    }
    __syncthreads();
    int nr = t >> 2, kc = (t & 3) * 16;
    uint32_t pk[8];
#pragma unroll
    for (int j = 0; j < 8; ++j) {
      pk[j] = (uint32_t)f2bf(tile[kc + 2 * j][nr]) | ((uint32_t)f2bf(tile[kc + 2 * j + 1][nr]) << 16);
    }
    uint4* dst = (uint4*)(Bt + (size_t)(nbase + nr) * Kpad + kbase + kc);
    dst[0] = make_uint4(pk[0], pk[1], pk[2], pk[3]);
    dst[1] = make_uint4(pk[4], pk[5], pk[6], pk[7]);
  } else if (b < 3296) {
    int idx = (b - 768) * 256 + t;
    if (idx < MPAD * 64) {
      int m = idx >> 6, k = idx & 63;
      xb[idx] = f2bf((m < NN && k < 50) ? x[m * 50 + k] : 0.f);
    }
  } else if (b < 3352) {
    int idx = (b - 3296) * 256 + t;  // exactly 14336 uint4
    ((uint4*)(bufX + (size_t)NN * 1024))[idx] = make_uint4(0, 0, 0, 0);
  } else if (b < 3470) {
    int idx = (b - 3352) * 256 + t;
    if (idx < 3 * NN + 1) cnt[idx] = 0;
  } else {
    int idx = (b - 3470) * 256 + t;
    if (idx < 4992) {
      float v = 0.f;
      if (idx < 2048)      { if (idx >= 1024) v = lb1[idx - 1024]; }
      else if (idx < 4096) { int j = idx - 2048; if (j >= 1024) v = lb2[j - 1024]; }
      else                 { int j = idx - 4096; if (j >= 768 && j < 889) v = lb3[j - 768]; }
      fb[idx] = v;
    }
  }
}

// ---------------- fused bf16 MFMA GEMM, BK=64; h half -> fp8, skip half -> bf16/fp32 ----------------
template <int OUT_S_BF16>
__global__ __launch_bounds__(256) void k_gemm_fused(
    const u16* __restrict__ A, const u16* __restrict__ Bt,
    const float* __restrict__ fbias,
    u8* __restrict__ outH, int ldH,
    void* __restrict__ outS, int ldS, int nsplit, int nrealS,
    int M, int Kpad, int NS) {
  __shared__ __align__(16) u16 lA[128 * 64];
  __shared__ __align__(16) u16 lB[128 * 64];
  int bid = blockIdx.x;
  int xcd = bid & 7, seq = bid >> 3;
  int nIdx = seq % NS, mloc = seq / NS;
  int mIdx = mloc * 8 + xcd;
  if (mIdx >= MT) return;
  int bm = mIdx * 128, bn = nIdx * 128;

  int t = threadIdx.x;
  int wave = t >> 6, lane = t & 63;
  int wm = (wave >> 1) * 64, wn = (wave & 1) * 64;

  f32x4 acc[4][4];
#pragma unroll
  for (int i = 0; i < 4; ++i)
#pragma unroll
    for (int j = 0; j < 4; ++j)
#pragma unroll
      for (int r = 0; r < 4; ++r) acc[i][j][r] = 0.f;

  int row = lane & 15, quad = lane >> 4;

  for (int k0 = 0; k0 < Kpad; k0 += 64) {
#pragma unroll
    for (int is = 0; is < 4; ++is) {
      int L = is * 256 + t;
      int m = L >> 3, c = L & 7;
      int j = c ^ (m & 7);
      const u16* gpA = A + (size_t)(bm + m) * Kpad + k0 + j * 8;
      const u16* gpB = Bt + (size_t)(bn + m) * Kpad + k0 + j * 8;
      u16* lpA = lA + (size_t)(is * 256 + wave * 64) * 8;
      u16* lpB = lB + (size_t)(is * 256 + wave * 64) * 8;
      __builtin_amdgcn_global_load_lds(
          (const __attribute__((address_space(1))) void*)gpA,
          (__attribute__((address_space(3))) void*)lpA, 16, 0, 0);
      __builtin_amdgcn_global_load_lds(
          (const __attribute__((address_space(1))) void*)gpB,
          (__attribute__((address_space(3))) void*)lpB, 16, 0, 0);
    }
    __syncthreads();

#pragma unroll
    for (int kk = 0; kk < 2; ++kk) {
      s16x8 af[4], bf[4];
#pragma unroll
      for (int mi = 0; mi < 4; ++mi) {
        int m = wm + mi * 16 + row;
        int c = (kk * 4 + quad) ^ (m & 7);
        af[mi] = *(const s16x8*)&lA[m * 64 + c * 8];
      }
#pragma unroll
      for (int ni = 0; ni < 4; ++ni) {
        int n = wn + ni * 16 + row;
        int c = (kk * 4 + quad) ^ (n & 7);
        bf[ni] = *(const s16x8*)&lB[n * 64 + c * 8];
      }
#pragma unroll
      for (int mi = 0; mi < 4; ++mi)
#pragma unroll
        for (int ni = 0; ni < 4; ++ni)
          acc[mi][ni] = __builtin_amdgcn_mfma_f32_16x16x32_bf16(af[mi], bf[ni], acc[mi][ni], 0, 0, 0);
    }
    __syncthreads();
  }

  int col = lane & 15, qr = (lane >> 4) * 4;
  bool isH = bn < nsplit;
#pragma unroll
  for (int mi = 0; mi < 4; ++mi) {
#pragma unroll
    for (int r = 0; r < 4; ++r) {
      int m = bm + wm + mi * 16 + qr + r;
      if (m >= M) continue;
#pragma unroll
      for (int ni = 0; ni < 4; ++ni) {
        int n = bn + wn + ni * 16 + col;
        float v = acc[mi][ni][r] + fbias[n];
        if (isH) {
          outH[(size_t)m * ldH + n] = f2fp8(v);
        } else {
          int c = n - nsplit;
          if (c < nrealS) {
            if (OUT_S_BF16) ((u16*)outS)[(size_t)m * ldS + c] = f2bf(v);
            else ((float*)outS)[(size_t)m * ldS + c] = v;
          }
        }
      }
    }
  }
}

// ---------------- per-node attention scores, C=256, H=4, ld=1024 (fp8 h) ----------------
__global__ void k_scores256(const u8* __restrict__ h, const float* __restrict__ a_src,
                            const float* __restrict__ a_dst, float* __restrict__ as_,
                            float* __restrict__ ad_) {
  int wid = (blockIdx.x * blockDim.x + threadIdx.x) >> 6;
  int lane = threadIdx.x & 63;
  if (wid >= NN * 4) return;
  int i = wid >> 2, hh = wid & 3;
  int pk = *(const int*)(h + (size_t)i * 1024 + hh * 256 + 4 * lane);
  float4 av = *(const float4*)(a_src + hh * 256 + 4 * lane);
  float4 dv = *(const float4*)(a_dst + hh * 256 + 4 * lane);
  float x0 = __builtin_amdgcn_cvt_f32_fp8(pk, 0);
  float x1 = __builtin_amdgcn_cvt_f32_fp8(pk, 1);
  float x2 = __builtin_amdgcn_cvt_f32_fp8(pk, 2);
  float x3 = __builtin_amdgcn_cvt_f32_fp8(pk, 3);
  float s1 = x0 * av.x + x1 * av.y + x2 * av.z + x3 * av.w;
  float s2 = x0 * dv.x + x1 * dv.y + x2 * dv.z + x3 * dv.w;
#pragma unroll
  for (int o = 32; o; o >>= 1) {
    s1 += __shfl_down(s1, o);
    s2 += __shfl_down(s2, o);
  }
  if (lane == 0) { as_[wid] = s1; ad_[wid] = s2; }
}

// ---------------- generic scores (layer 3: H=6, C=121, ld=768, fp8 h) ----------------
__global__ void k_scores(const u8* __restrict__ h, const float* __restrict__ a_src,
                         const float* __restrict__ a_dst, float* __restrict__ as_,
                         float* __restrict__ ad_, int H, int C, int ld) {
  int wid = (blockIdx.x * blockDim.x + threadIdx.x) >> 6;
  int lane = threadIdx.x & 63;
  if (wid >= NN * H) return;
  int i = wid / H, hh = wid - i * H;
  const u8* hp = h + (size_t)i * ld + hh * C;
  const float* sp = a_src + hh * C;
  const float* dp = a_dst + hh * C;
  float s1 = 0.f, s2 = 0.f;
  for (int c = lane; c < C; c += 64) {
    float v = __builtin_amdgcn_cvt_f32_fp8((int)hp[c], 0);
    s1 += v * sp[c];
    s2 += v * dp[c];
  }
#pragma unroll
  for (int o = 32; o; o >>= 1) {
    s1 += __shfl_down(s1, o);
    s2 += __shfl_down(s2, o);
  }
  if (lane == 0) { as_[wid] = s1; ad_[wid] = s2; }
}

// ---------------- agg + softmax, concat layers (H=4, F=1024, fp8 h) ----------------
__global__ __launch_bounds__(256) void k_agg_cat(
    const u8* __restrict__ h, const float* __restrict__ as_, const float* __restrict__ ad_,
    const int* __restrict__ off, const int* __restrict__ csr_src,
    const float* __restrict__ bias, const u16* __restrict__ skip, u16* __restrict__ outx) {
  const int F = 1024;
  int i = blockIdx.x, t = threadIdx.x;
  int start = off[i], end = off[i + 1];
  int wave = t >> 6, lane = t & 63;
  __shared__ int src_s[CAP];
  __shared__ float a_s[CAP][4];
  float4 adv = *(const float4*)(ad_ + (size_t)i * 4);
  float m_run = -1e30f, denom = 0.f;
  float acc0 = 0.f, acc1 = 0.f, acc2 = 0.f, acc3 = 0.f;
  for (int e0 = start; e0 < end; e0 += CAP) {
    int ne = min(CAP, end - e0);
    if (e0 > start) __syncthreads();
    if (t < ne) {
      int s = csr_src[e0 + t];
      src_s[t] = s;
      float4 av = *(const float4*)(as_ + (size_t)s * 4);
      a_s[t][0] = lrelu02(av.x + adv.x);
      a_s[t][1] = lrelu02(av.y + adv.y);
      a_s[t][2] = lrelu02(av.z + adv.z);
      a_s[t][3] = lrelu02(av.w + adv.w);
    }
    __syncthreads();
    float cm = -1e30f;
    for (int j = lane; j < ne; j += 64) cm = fmaxf(cm, a_s[j][wave]);
#pragma unroll
    for (int msk = 32; msk; msk >>= 1) cm = fmaxf(cm, __shfl_xor(cm, msk));
    float nm = fmaxf(m_run, cm);
    float sm = 0.f;
    for (int j = lane; j < ne; j += 64) {
      float e = __expf(a_s[j][wave] - nm);
      a_s[j][wave] = e;
      sm += e;
    }
#pragma unroll
    for (int msk = 32; msk; msk >>= 1) sm += __shfl_xor(sm, msk);
    float rs = __expf(m_run - nm);
    acc0 *= rs; acc1 *= rs; acc2 *= rs; acc3 *= rs;
    denom = denom * rs + sm;
    m_run = nm;
#pragma unroll 4
    for (int e = 0; e < ne; ++e) {
      int pk = *(const int*)(h + (size_t)src_s[e] * F + 4 * t);
      float ww = a_s[e][wave];
      acc0 += ww * __builtin_amdgcn_cvt_f32_fp8(pk, 0);
      acc1 += ww * __builtin_amdgcn_cvt_f32_fp8(pk, 1);
      acc2 += ww * __builtin_amdgcn_cvt_f32_fp8(pk, 2);
      acc3 += ww * __builtin_amdgcn_cvt_f32_fp8(pk, 3);
    }
  }
  float rdm = 1.f / (denom + 1e-16f);
  int ch = 4 * t;
  float4 bb = *(const float4*)(bias + ch);
  uint2 sk = *(const uint2*)(skip + (size_t)i * F + ch);
  u16 o0 = f2bf(eluf(acc0 * rdm + bb.x + b2f_lo(sk.x)));
  u16 o1 = f2bf(eluf(acc1 * rdm + bb.y + b2f_hi(sk.x)));
  u16 o2 = f2bf(eluf(acc2 * rdm + bb.z + b2f_lo(sk.y)));
  u16 o3 = f2bf(eluf(acc3 * rdm + bb.w + b2f_hi(sk.y)));
  uint2 ov;
  ov.x = (uint32_t)o0 | ((uint32_t)o1 << 16);
  ov.y = (uint32_t)o2 | ((uint32_t)o3 << 16);
  *(uint2*)(outx + (size_t)i * F + ch) = ov;
}

// ---------------- agg + softmax, mean layer (H=6, C=121, stride 768, fp8 h) ----------------
__global__ __launch_bounds__(256) void k_agg_mean(
    const u8* __restrict__ h, const float* __restrict__ as_, const float* __restrict__ ad_,
    const int* __restrict__ off, const int* __restrict__ csr_src,
    const float* __restrict__ bias, float* __restrict__ out) {
  const int H = 6, C = 121, FP = 768;
  int i = blockIdx.x, t = threadIdx.x;
  int start = off[i], end = off[i + 1];
  int wave = t >> 6, lane = t & 63;
  __shared__ int src_s[CAP];
  __shared__ float a_s[CAP][H];
  __shared__ float nm_s[H], sm_s[H];
  __shared__ float agg_s[FP];
  float adv[H];
  {
    float2 v0 = *(const float2*)(ad_ + (size_t)i * H);
    float2 v1 = *(const float2*)(ad_ + (size_t)i * H + 2);
    float2 v2 = *(const float2*)(ad_ + (size_t)i * H + 4);
    adv[0] = v0.x; adv[1] = v0.y; adv[2] = v1.x; adv[3] = v1.y; adv[4] = v2.x; adv[5] = v2.y;
  }
  int c0 = 4 * t;
  bool act = t < 192;
  int hd[4];
#pragma unroll
  for (int r = 0; r < 4; ++r) {
    int c = c0 + r;
    hd[r] = (act && c < 726) ? (c / C) : 0;
  }
  float acc[4] = {0.f, 0.f, 0.f, 0.f};
  float m_r[4] = {-1e30f, -1e30f, -1e30f, -1e30f};
  float d_r[4] = {0.f, 0.f, 0.f, 0.f};
  for (int e0 = start; e0 < end; e0 += CAP) {
    int ne = min(CAP, end - e0);
    if (e0 > start) __syncthreads();
    if (t < ne) {
      int s = csr_src[e0 + t];
      src_s[t] = s;
      float2 v0 = *(const float2*)(as_ + (size_t)s * H);
      float2 v1 = *(const float2*)(as_ + (size_t)s * H + 2);
      float2 v2 = *(const float2*)(as_ + (size_t)s * H + 4);
      a_s[t][0] = lrelu02(v0.x + adv[0]);
      a_s[t][1] = lrelu02(v0.y + adv[1]);
      a_s[t][2] = lrelu02(v1.x + adv[2]);
      a_s[t][3] = lrelu02(v1.y + adv[3]);
      a_s[t][4] = lrelu02(v2.x + adv[4]);
      a_s[t][5] = lrelu02(v2.y + adv[5]);
    }
    __syncthreads();
    for (int hh = wave; hh < H; hh += 4) {
      float cm = -1e30f;
      for (int j = lane; j < ne; j += 64) cm = fmaxf(cm, a_s[j][hh]);
#pragma unroll
      for (int msk = 32; msk; msk >>= 1) cm = fmaxf(cm, __shfl_xor(cm, msk));
      float sm = 0.f;
      for (int j = lane; j < ne; j += 64) {
        float e = __expf(a_s[j][hh] - cm);   // chunk-local max
        a_s[j][hh] = e;
        sm += e;
      }
#pragma unroll
      for (int msk = 32; msk; msk >>= 1) sm += __shfl_xor(sm, msk);
      if (lane == 0) { nm_s[hh] = cm; sm_s[hh] = sm; }
    }
    __syncthreads();
    if (act) {
      float rsn[4];
#pragma unroll
      for (int r = 0; r < 4; ++r) {
        float cm = nm_s[hd[r]];
        float nm = fmaxf(m_r[r], cm);
        float rs_old = __expf(m_r[r] - nm);
        float rs_new = __expf(cm - nm);
        acc[r] *= rs_old;
        d_r[r] = d_r[r] * rs_old + sm_s[hd[r]] * rs_new;
        m_r[r] = nm;
        rsn[r] = rs_new;
      }
#pragma unroll 4
      for (int e = 0; e < ne; ++e) {
        const u8* hp = h + (size_t)src_s[e] * FP;
        int pk = *(const int*)(hp + c0);
        acc[0] += rsn[0] * a_s[e][hd[0]] * __builtin_amdgcn_cvt_f32_fp8(pk, 0);
        acc[1] += rsn[1] * a_s[e][hd[1]] * __builtin_amdgcn_cvt_f32_fp8(pk, 1);
        acc[2] += rsn[2] * a_s[e][hd[2]] * __builtin_amdgcn_cvt_f32_fp8(pk, 2);
        acc[3] += rsn[3] * a_s[e][hd[3]] * __builtin_amdgcn_cvt_f32_fp8(pk, 3);
      }
    }
  }
  __syncthreads();
  if (act) {
#pragma unroll
    for (int r = 0; r < 4; ++r) agg_s[c0 + r] = acc[r] / (d_r[r] + 1e-16f);
  }
  __syncthreads();
  if (t < C) {
    float s = 0.f;
#pragma unroll
    for (int hh = 0; hh < H; ++hh) s += agg_s[hh * C + t];
    size_t idx = (size_t)i * C + t;
    out[idx] += s * (1.f / 6.f) + bias[t];
  }
}

// ---------------- launch ----------------
extern "C" void kernel_launch(void* const* d_in, const int* in_sizes, int n_in,
                              void* d_out, int out_size, void* d_ws, size_t ws_size,
                              hipStream_t stream) {
  const float* x = (const float*)d_in[0];
  const int* ei = (const int*)d_in[1];
  const float* W1 = (const float*)d_in[2];
  const float* a_src1 = (const float*)d_in[3];
  const float* a_dst1 = (const float*)d_in[4];
  const float* b1 = (const float*)d_in[5];
  const float* lW1 = (const float*)d_in[6];
  const float* lb1 = (const float*)d_in[7];
  const float* W2 = (const float*)d_in[8];
  const float* a_src2 = (const float*)d_in[9];
  const float* a_dst2 = (const float*)d_in[10];
  const float* b2 = (const float*)d_in[11];
  const float* lW2 = (const float*)d_in[12];
  const float* lb2 = (const float*)d_in[13];
  const float* W3 = (const float*)d_in[14];
  const float* a_src3 = (const float*)d_in[15];
  const float* a_dst3 = (const float*)d_in[16];
  const float* b3 = (const float*)d_in[17];
  const float* lW3 = (const float*)d_in[18];
  const float* lb3 = (const float*)d_in[19];
  float* outp = (float*)d_out;

  char* ws = (char*)d_ws;
  size_t o = 0;
  auto alloc = [&](size_t bytes) { void* p = ws + o; o += (bytes + 255) & ~(size_t)255; return p; };
  u8* bufH8 = (u8*)alloc((size_t)MPAD * 1024);        // GAT-branch h (fp8)
  u16* bufX = (u16*)alloc((size_t)MPAD * 1024 * 2);   // layer output / GEMM A (bf16)
  u16* bufS = (u16*)alloc((size_t)NN * 1024 * 2);     // dense skip (bf16)
  u16* xb16 = (u16*)alloc((size_t)MPAD * 64 * 2);
  u16* wtc1 = (u16*)alloc((size_t)2048 * 64 * 2);
  u16* wtc2 = (u16*)alloc((size_t)2048 * 1024 * 2);
  u16* wtc3 = (u16*)alloc((size_t)896 * 1024 * 2);
  float* fb12 = (float*)alloc((size_t)4992 * 4);
  float* fb1 = fb12;
  float* fb2 = fb12 + 2048;
  float* fb3 = fb12 + 4096;
  float* as_ = (float*)alloc((size_t)NN * 6 * 4);
  float* ad_ = (float*)alloc((size_t)NN * 6 * 4);
  int* cnt = (int*)alloc((size_t)(3 * NN + 1) * 4);
  int* offs = cnt + NN;
  int* cursor = offs + NN + 1;
  int* csr_src = (int*)alloc((size_t)EN_ * 4);

  // ---- prep (everything) + CSR build ----
  k_prep<<<PREP_BLOCKS, 256, 0, stream>>>(x, xb16, W1, lW1, W2, lW2, W3, lW3,
                                          wtc1, wtc2, wtc3, lb1, lb2, lb3, fb12,
                                          bufX, cnt);
  int eb = (EN_ + 255) / 256;
  k_count<<<eb, 256, 0, stream>>>(ei, cnt);
  k_scan<<<1, 1024, 0, stream>>>(cnt, offs);
  k_fill<<<eb, 256, 0, stream>>>(ei, offs, cursor, csr_src);

  // ---- Layer 1 (fused N=2048, Kpad=64) ----
  {
    k_gemm_fused<1><<<16 * 80, 256, 0, stream>>>(
        xb16, wtc1, fb1, bufH8, 1024, bufS, 1024, 1024, 1024, NN, 64, 16);
    k_scores256<<<10000, 256, 0, stream>>>(bufH8, a_src1, a_dst1, as_, ad_);
    k_agg_cat<<<NN, 256, 0, stream>>>(bufH8, as_, ad_, offs, csr_src, b1, bufS, bufX);
  }
  // ---- Layer 2 (fused N=2048, Kpad=1024) ----
  {
    k_gemm_fused<1><<<16 * 80, 256, 0, stream>>>(
        bufX, wtc2, fb2, bufH8, 1024, bufS, 1024, 1024, 1024, NN, 1024, 16);
    k_scores256<<<10000, 256, 0, stream>>>(bufH8, a_src2, a_dst2, as_, ad_);
    k_agg_cat<<<NN, 256, 0, stream>>>(bufH8, as_, ad_, offs, csr_src, b2, bufS, bufX);
  }
  // ---- Layer 3 (fused N=896) ----
  {
    k_gemm_fused<0><<<7 * 80, 256, 0, stream>>>(
        bufX, wtc3, fb3, bufH8, 768, outp, 121, 768, 121, NN, 1024, 7);
    k_scores<<<(NN * 6 + 3) / 4, 256, 0, stream>>>(bufH8, a_src3, a_dst3, as_, ad_, 6, 121, 768);
    k_agg_mean<<<NN, 256, 0, stream>>>(bufH8, as_, ad_, offs, csr_src, b3, outp);
  }
}

// Round 10
// 388.209 us; speedup vs baseline: 1.0739x; 1.0739x over previous
//
#include <hip/hip_runtime.h>
#include <cstdint>
#include <cstddef>

#define NN 10000
#define EE 160000
#define EN_ (EE + NN)
#define MPAD 10112   // 79 * 128
#define MT 79        // M tiles
#define CAP 128      // agg edge-chunk (max deg ~45 -> single chunk)

typedef short s16x8 __attribute__((ext_vector_type(8)));
typedef float f32x4 __attribute__((ext_vector_type(4)));
typedef unsigned short u16;
typedef unsigned char u8;

__device__ __forceinline__ u16 f2bf(float f) {
  uint32_t u = __float_as_uint(f);
  uint32_t r = (u + 0x7fffu + ((u >> 16) & 1u)) >> 16;
  return (u16)r;
}
__device__ __forceinline__ float b2f_lo(uint32_t p) { return __uint_as_float(p << 16); }
__device__ __forceinline__ float b2f_hi(uint32_t p) { return __uint_as_float(p & 0xffff0000u); }
__device__ __forceinline__ float lrelu02(float x) { return x > 0.f ? x : 0.2f * x; }
__device__ __forceinline__ float eluf(float x) { return x > 0.f ? x : (__expf(x) - 1.f); }
__device__ __forceinline__ u8 f2fp8(float v) {
  v = fminf(fmaxf(v, -448.f), 448.f);
  return (u8)(__builtin_amdgcn_cvt_pk_fp8_f32(v, v, 0, false) & 0xff);
}

// ---------------- CSR scan/fill ----------------
__global__ __launch_bounds__(1024) void k_scan(const int* __restrict__ cnt, int* __restrict__ off) {
  __shared__ int sums[1024];
  int t = threadIdx.x;
  const int per = (NN + 1023) / 1024;  // 10
  int base = t * per;
  int local = 0;
  for (int j = 0; j < per; ++j) {
    int idx = base + j;
    if (idx < NN) local += cnt[idx];
  }
  sums[t] = local;
  __syncthreads();
  for (int s = 1; s < 1024; s <<= 1) {
    int v = (t >= s) ? sums[t - s] : 0;
    __syncthreads();
    sums[t] += v;
    __syncthreads();
  }
  int run = (t == 0) ? 0 : sums[t - 1];
  for (int j = 0; j < per; ++j) {
    int idx = base + j;
    if (idx < NN) { off[idx] = run; run += cnt[idx]; }
  }
  if (t == 1023) off[NN] = EN_;
}

__global__ void k_fill(const int* __restrict__ ei, const int* __restrict__ off,
                       int* __restrict__ cursor, int* __restrict__ csr_src) {
  int e = blockIdx.x * blockDim.x + threadIdx.x;
  if (e >= EN_) return;
  int s, d;
  if (e < EE) { s = ei[e]; d = ei[EE + e]; } else { s = d = e - EE; }
  int p = atomicAdd(&cursor[d], 1);
  csr_src[off[d] + p] = s;
}

// ---------------- mega prep (incl. edge count; cnt pre-zeroed by memset) ----------------
// [0,768) transposes | [768,3296) x2b | [3296,3352) bufX pad | [3352,3372) fb
// [3372,4037) edge count
#define PREP_BLOCKS 4037
__global__ __launch_bounds__(256) void k_prep(
    const float* __restrict__ x, u16* __restrict__ xb,
    const float* __restrict__ W1, const float* __restrict__ lW1,
    const float* __restrict__ W2, const float* __restrict__ lW2,
    const float* __restrict__ W3, const float* __restrict__ lW3,
    u16* __restrict__ wtc1, u16* __restrict__ wtc2, u16* __restrict__ wtc3,
    const float* __restrict__ lb1, const float* __restrict__ lb2,
    const float* __restrict__ lb3, float* __restrict__ fb,
    u16* __restrict__ bufX, const int* __restrict__ ei, int* __restrict__ cnt) {
  int b = blockIdx.x, t = threadIdx.x;
  if (b < 768) {
    const float* W; u16* Bt; int K, N, Kpad, nb, kb;
    if (b < 16)       { W = W1;  Bt = wtc1;                       K = 50;   N = 1024; Kpad = 64;   nb = b;      kb = 0; }
    else if (b < 32)  { W = lW1; Bt = wtc1 + (size_t)1024 * 64;   K = 50;   N = 1024; Kpad = 64;   nb = b - 16; kb = 0; }
    else if (b < 288) { int r = b - 32;  W = W2;  Bt = wtc2;                         K = 1024; N = 1024; Kpad = 1024; nb = r & 15; kb = r >> 4; }
    else if (b < 544) { int r = b - 288; W = lW2; Bt = wtc2 + (size_t)1024 * 1024;   K = 1024; N = 1024; Kpad = 1024; nb = r & 15; kb = r >> 4; }
    else if (b < 736) { int r = b - 544; W = W3;  Bt = wtc3;                         K = 1024; N = 726;  Kpad = 1024; nb = r % 12; kb = r / 12; }
    else              { int r = b - 736; W = lW3; Bt = wtc3 + (size_t)768 * 1024;    K = 1024; N = 121;  Kpad = 1024; nb = r & 1;  kb = r >> 1; }
    __shared__ float tile[64][65];
    int kbase = kb * 64, nbase = nb * 64;
    int nl = t & 63, kl0 = t >> 6;
#pragma unroll
    for (int j = 0; j < 16; ++j) {
      int k = kbase + kl0 + j * 4, n = nbase + nl;
      tile[kl0 + j * 4][nl] = (k < K && n < N) ? W[(size_t)k * N + n] : 0.f;
    }
    __syncthreads();
    int nr = t >> 2, kc = (t & 3) * 16;
    uint32_t pk[8];
#pragma unroll
    for (int j = 0; j < 8; ++j) {
      pk[j] = (uint32_t)f2bf(tile[kc + 2 * j][nr]) | ((uint32_t)f2bf(tile[kc + 2 * j + 1][nr]) << 16);
    }
    uint4* dst = (uint4*)(Bt + (size_t)(nbase + nr) * Kpad + kbase + kc);
    dst[0] = make_uint4(pk[0], pk[1], pk[2], pk[3]);
    dst[1] = make_uint4(pk[4], pk[5], pk[6], pk[7]);
  } else if (b < 3296) {
    int idx = (b - 768) * 256 + t;
    if (idx < MPAD * 64) {
      int m = idx >> 6, k = idx & 63;
      xb[idx] = f2bf((m < NN && k < 50) ? x[m * 50 + k] : 0.f);
    }
  } else if (b < 3352) {
    int idx = (b - 3296) * 256 + t;  // exactly 14336 uint4
    ((uint4*)(bufX + (size_t)NN * 1024))[idx] = make_uint4(0, 0, 0, 0);
  } else if (b < 3372) {
    int idx = (b - 3352) * 256 + t;
    if (idx < 4992) {
      float v = 0.f;
      if (idx < 2048)      { if (idx >= 1024) v = lb1[idx - 1024]; }
      else if (idx < 4096) { int j = idx - 2048; if (j >= 1024) v = lb2[j - 1024]; }
      else                 { int j = idx - 4096; if (j >= 768 && j < 889) v = lb3[j - 768]; }
      fb[idx] = v;
    }
  } else {
    int e = (b - 3372) * 256 + t;
    if (e < EN_) {
      int d = (e < EE) ? ei[EE + e] : (e - EE);
      atomicAdd(&cnt[d], 1);
    }
  }
}

// ---------------- fused bf16 MFMA GEMM, BK=64; packed-store epilogue ----------------
template <int OUT_S_BF16>
__global__ __launch_bounds__(256) void k_gemm_fused(
    const u16* __restrict__ A, const u16* __restrict__ Bt,
    const float* __restrict__ fbias,
    u8* __restrict__ outH, int ldH,
    void* __restrict__ outS, int ldS, int nsplit, int nrealS,
    int M, int Kpad, int NS) {
  __shared__ __align__(16) u16 lA[128 * 64];
  __shared__ __align__(16) u16 lB[128 * 64];
  int bid = blockIdx.x;
  int xcd = bid & 7, seq = bid >> 3;
  int nIdx = seq % NS, mloc = seq / NS;
  int mIdx = mloc * 8 + xcd;
  if (mIdx >= MT) return;
  int bm = mIdx * 128, bn = nIdx * 128;

  int t = threadIdx.x;
  int wave = t >> 6, lane = t & 63;
  int wm = (wave >> 1) * 64, wn = (wave & 1) * 64;

  f32x4 acc[4][4];
#pragma unroll
  for (int i = 0; i < 4; ++i)
#pragma unroll
    for (int j = 0; j < 4; ++j)
#pragma unroll
      for (int r = 0; r < 4; ++r) acc[i][j][r] = 0.f;

  int row = lane & 15, quad = lane >> 4;

  for (int k0 = 0; k0 < Kpad; k0 += 64) {
#pragma unroll
    for (int is = 0; is < 4; ++is) {
      int L = is * 256 + t;
      int m = L >> 3, c = L & 7;
      int j = c ^ (m & 7);
      const u16* gpA = A + (size_t)(bm + m) * Kpad + k0 + j * 8;
      const u16* gpB = Bt + (size_t)(bn + m) * Kpad + k0 + j * 8;
      u16* lpA = lA + (size_t)(is * 256 + wave * 64) * 8;
      u16* lpB = lB + (size_t)(is * 256 + wave * 64) * 8;
      __builtin_amdgcn_global_load_lds(
          (const __attribute__((address_space(1))) void*)gpA,
          (__attribute__((address_space(3))) void*)lpA, 16, 0, 0);
      __builtin_amdgcn_global_load_lds(
          (const __attribute__((address_space(1))) void*)gpB,
          (__attribute__((address_space(3))) void*)lpB, 16, 0, 0);
    }
    __syncthreads();

#pragma unroll
    for (int kk = 0; kk < 2; ++kk) {
      s16x8 af[4], bf[4];
#pragma unroll
      for (int mi = 0; mi < 4; ++mi) {
        int m = wm + mi * 16 + row;
        int c = (kk * 4 + quad) ^ (m & 7);
        af[mi] = *(const s16x8*)&lA[m * 64 + c * 8];
      }
#pragma unroll
      for (int ni = 0; ni < 4; ++ni) {
        int n = wn + ni * 16 + row;
        int c = (kk * 4 + quad) ^ (n & 7);
        bf[ni] = *(const s16x8*)&lB[n * 64 + c * 8];
      }
#pragma unroll
      for (int mi = 0; mi < 4; ++mi)
#pragma unroll
        for (int ni = 0; ni < 4; ++ni)
          acc[mi][ni] = __builtin_amdgcn_mfma_f32_16x16x32_bf16(af[mi], bf[ni], acc[mi][ni], 0, 0, 0);
    }
    __syncthreads();
  }

  // ---- epilogue: quad-transpose via dword shfl, packed stores ----
  int col16 = lane & 15, qr = (lane >> 4) * 4;
  int qbase = lane & 48;
  bool isH = bn < nsplit;
  int srcs[4];
#pragma unroll
  for (int k = 0; k < 4; ++k) srcs[k] = qbase | ((4 * col16 + k) & 15);
  int bsel = col16 >> 2;  // requester's reg index (const across k)
  if (isH) {
#pragma unroll
    for (int mi = 0; mi < 4; ++mi) {
#pragma unroll
      for (int r = 0; r < 4; ++r) {
        int m = bm + wm + mi * 16 + qr + r;
        float vc[4];
#pragma unroll
        for (int ni = 0; ni < 4; ++ni) {
          float v = acc[mi][ni][r] + fbias[bn + wn + ni * 16 + col16];
          vc[ni] = fminf(fmaxf(v, -448.f), 448.f);
        }
        uint32_t D = (uint32_t)__builtin_amdgcn_cvt_pk_fp8_f32(vc[0], vc[1], 0, false);
        D = (uint32_t)__builtin_amdgcn_cvt_pk_fp8_f32(vc[2], vc[3], D, true);
        uint32_t outw = 0;
#pragma unroll
        for (int k = 0; k < 4; ++k) {
          uint32_t rk = (uint32_t)__shfl((int)D, srcs[k]);
          outw |= ((rk >> (8 * bsel)) & 0xffu) << (8 * k);
        }
        if (m < M)
          *(uint32_t*)(outH + (size_t)m * ldH + (bn + wn + 4 * col16)) = outw;
      }
    }
  } else {
#pragma unroll
    for (int mi = 0; mi < 4; ++mi) {
#pragma unroll
      for (int r = 0; r < 4; ++r) {
        int m = bm + wm + mi * 16 + qr + r;
        float vv[4];
#pragma unroll
        for (int ni = 0; ni < 4; ++ni)
          vv[ni] = acc[mi][ni][r] + fbias[bn + wn + ni * 16 + col16];
        if (OUT_S_BF16) {
          uint32_t D0 = (uint32_t)f2bf(vv[0]) | ((uint32_t)f2bf(vv[1]) << 16);
          uint32_t D1 = (uint32_t)f2bf(vv[2]) | ((uint32_t)f2bf(vv[3]) << 16);
          uint32_t lo = 0, hi = 0;
#pragma unroll
          for (int k = 0; k < 4; ++k) {
            uint32_t ra = (uint32_t)__shfl((int)D0, srcs[k]);
            uint32_t rb = (uint32_t)__shfl((int)D1, srcs[k]);
            uint32_t rw = (bsel & 2) ? rb : ra;
            uint32_t h16 = (rw >> (16 * (bsel & 1))) & 0xffffu;
            if (k < 2) lo |= h16 << (16 * k);
            else hi |= h16 << (16 * (k - 2));
          }
          if (m < M) {
            int cg = bn + wn + 4 * col16 - nsplit;  // layers 1-2: always < nrealS
            uint2 ov; ov.x = lo; ov.y = hi;
            *(uint2*)((u16*)outS + (size_t)m * ldS + cg) = ov;
          }
        } else {
#pragma unroll
          for (int ni = 0; ni < 4; ++ni) {
            int c = bn + wn + ni * 16 + col16 - nsplit;
            if (m < M && c < nrealS)
              ((float*)outS)[(size_t)m * ldS + c] = vv[ni];
          }
        }
      }
    }
  }
}

// ---------------- per-node attention scores, C=256, H=4, ld=1024 (fp8 h) ----------------
__global__ void k_scores256(const u8* __restrict__ h, const float* __restrict__ a_src,
                            const float* __restrict__ a_dst, float* __restrict__ as_,
                            float* __restrict__ ad_) {
  int wid = (blockIdx.x * blockDim.x + threadIdx.x) >> 6;
  int lane = threadIdx.x & 63;
  if (wid >= NN * 4) return;
  int i = wid >> 2, hh = wid & 3;
  int pk = *(const int*)(h + (size_t)i * 1024 + hh * 256 + 4 * lane);
  float4 av = *(const float4*)(a_src + hh * 256 + 4 * lane);
  float4 dv = *(const float4*)(a_dst + hh * 256 + 4 * lane);
  float x0 = __builtin_amdgcn_cvt_f32_fp8(pk, 0);
  float x1 = __builtin_amdgcn_cvt_f32_fp8(pk, 1);
  float x2 = __builtin_amdgcn_cvt_f32_fp8(pk, 2);
  float x3 = __builtin_amdgcn_cvt_f32_fp8(pk, 3);
  float s1 = x0 * av.x + x1 * av.y + x2 * av.z + x3 * av.w;
  float s2 = x0 * dv.x + x1 * dv.y + x2 * dv.z + x3 * dv.w;
#pragma unroll
  for (int o = 32; o; o >>= 1) {
    s1 += __shfl_down(s1, o);
    s2 += __shfl_down(s2, o);
  }
  if (lane == 0) { as_[wid] = s1; ad_[wid] = s2; }
}

// ---------------- generic scores (layer 3: H=6, C=121, ld=768, fp8 h) ----------------
__global__ void k_scores(const u8* __restrict__ h, const float* __restrict__ a_src,
                         const float* __restrict__ a_dst, float* __restrict__ as_,
                         float* __restrict__ ad_, int H, int C, int ld) {
  int wid = (blockIdx.x * blockDim.x + threadIdx.x) >> 6;
  int lane = threadIdx.x & 63;
  if (wid >= NN * H) return;
  int i = wid / H, hh = wid - i * H;
  const u8* hp = h + (size_t)i * ld + hh * C;
  const float* sp = a_src + hh * C;
  const float* dp = a_dst + hh * C;
  float s1 = 0.f, s2 = 0.f;
  for (int c = lane; c < C; c += 64) {
    float v = __builtin_amdgcn_cvt_f32_fp8((int)hp[c], 0);
    s1 += v * sp[c];
    s2 += v * dp[c];
  }
#pragma unroll
  for (int o = 32; o; o >>= 1) {
    s1 += __shfl_down(s1, o);
    s2 += __shfl_down(s2, o);
  }
  if (lane == 0) { as_[wid] = s1; ad_[wid] = s2; }
}

// ---------------- agg + softmax, concat layers (H=4, F=1024, fp8 h) ----------------
__global__ __launch_bounds__(256) void k_agg_cat(
    const u8* __restrict__ h, const float* __restrict__ as_, const float* __restrict__ ad_,
    const int* __restrict__ off, const int* __restrict__ csr_src,
    const float* __restrict__ bias, const u16* __restrict__ skip, u16* __restrict__ outx) {
  const int F = 1024;
  int i = blockIdx.x, t = threadIdx.x;
  int start = off[i], end = off[i + 1];
  int wave = t >> 6, lane = t & 63;
  __shared__ int src_s[CAP];
  __shared__ float a_s[CAP][4];
  float4 adv = *(const float4*)(ad_ + (size_t)i * 4);
  float m_run = -1e30f, denom = 0.f;
  float acc0 = 0.f, acc1 = 0.f, acc2 = 0.f, acc3 = 0.f;
  for (int e0 = start; e0 < end; e0 += CAP) {
    int ne = min(CAP, end - e0);
    if (e0 > start) __syncthreads();
    if (t < ne) {
      int s = csr_src[e0 + t];
      src_s[t] = s;
      float4 av = *(const float4*)(as_ + (size_t)s * 4);
      a_s[t][0] = lrelu02(av.x + adv.x);
      a_s[t][1] = lrelu02(av.y + adv.y);
      a_s[t][2] = lrelu02(av.z + adv.z);
      a_s[t][3] = lrelu02(av.w + adv.w);
    }
    __syncthreads();
    float cm = -1e30f;
    for (int j = lane; j < ne; j += 64) cm = fmaxf(cm, a_s[j][wave]);
#pragma unroll
    for (int msk = 32; msk; msk >>= 1) cm = fmaxf(cm, __shfl_xor(cm, msk));
    float nm = fmaxf(m_run, cm);
    float sm = 0.f;
    for (int j = lane; j < ne; j += 64) {
      float e = __expf(a_s[j][wave] - nm);
      a_s[j][wave] = e;
      sm += e;
    }
#pragma unroll
    for (int msk = 32; msk; msk >>= 1) sm += __shfl_xor(sm, msk);
    float rs = __expf(m_run - nm);
    acc0 *= rs; acc1 *= rs; acc2 *= rs; acc3 *= rs;
    denom = denom * rs + sm;
    m_run = nm;
#pragma unroll 4
    for (int e = 0; e < ne; ++e) {
      int pk = *(const int*)(h + (size_t)src_s[e] * F + 4 * t);
      float ww = a_s[e][wave];
      acc0 += ww * __builtin_amdgcn_cvt_f32_fp8(pk, 0);
      acc1 += ww * __builtin_amdgcn_cvt_f32_fp8(pk, 1);
      acc2 += ww * __builtin_amdgcn_cvt_f32_fp8(pk, 2);
      acc3 += ww * __builtin_amdgcn_cvt_f32_fp8(pk, 3);
    }
  }
  float rdm = 1.f / (denom + 1e-16f);
  int ch = 4 * t;
  float4 bb = *(const float4*)(bias + ch);
  uint2 sk = *(const uint2*)(skip + (size_t)i * F + ch);
  u16 o0 = f2bf(eluf(acc0 * rdm + bb.x + b2f_lo(sk.x)));
  u16 o1 = f2bf(eluf(acc1 * rdm + bb.y + b2f_hi(sk.x)));
  u16 o2 = f2bf(eluf(acc2 * rdm + bb.z + b2f_lo(sk.y)));
  u16 o3 = f2bf(eluf(acc3 * rdm + bb.w + b2f_hi(sk.y)));
  uint2 ov;
  ov.x = (uint32_t)o0 | ((uint32_t)o1 << 16);
  ov.y = (uint32_t)o2 | ((uint32_t)o3 << 16);
  *(uint2*)(outx + (size_t)i * F + ch) = ov;
}

// ---------------- agg + softmax, mean layer (H=6, C=121, stride 768, fp8 h) ----------------
__global__ __launch_bounds__(256) void k_agg_mean(
    const u8* __restrict__ h, const float* __restrict__ as_, const float* __restrict__ ad_,
    const int* __restrict__ off, const int* __restrict__ csr_src,
    const float* __restrict__ bias, float* __restrict__ out) {
  const int H = 6, C = 121, FP = 768;
  int i = blockIdx.x, t = threadIdx.x;
  int start = off[i], end = off[i + 1];
  int wave = t >> 6, lane = t & 63;
  __shared__ int src_s[CAP];
  __shared__ float a_s[CAP][H];
  __shared__ float nm_s[H], sm_s[H];
  __shared__ float agg_s[FP];
  float adv[H];
  {
    float2 v0 = *(const float2*)(ad_ + (size_t)i * H);
    float2 v1 = *(const float2*)(ad_ + (size_t)i * H + 2);
    float2 v2 = *(const float2*)(ad_ + (size_t)i * H + 4);
    adv[0] = v0.x; adv[1] = v0.y; adv[2] = v1.x; adv[3] = v1.y; adv[4] = v2.x; adv[5] = v2.y;
  }
  int c0 = 4 * t;
  bool act = t < 192;
  int hd[4];
#pragma unroll
  for (int r = 0; r < 4; ++r) {
    int c = c0 + r;
    hd[r] = (act && c < 726) ? (c / C) : 0;
  }
  float acc[4] = {0.f, 0.f, 0.f, 0.f};
  float m_r[4] = {-1e30f, -1e30f, -1e30f, -1e30f};
  float d_r[4] = {0.f, 0.f, 0.f, 0.f};
  for (int e0 = start; e0 < end; e0 += CAP) {
    int ne = min(CAP, end - e0);
    if (e0 > start) __syncthreads();
    if (t < ne) {
      int s = csr_src[e0 + t];
      src_s[t] = s;
      float2 v0 = *(const float2*)(as_ + (size_t)s * H);
      float2 v1 = *(const float2*)(as_ + (size_t)s * H + 2);
      float2 v2 = *(const float2*)(as_ + (size_t)s * H + 4);
      a_s[t][0] = lrelu02(v0.x + adv[0]);
      a_s[t][1] = lrelu02(v0.y + adv[1]);
      a_s[t][2] = lrelu02(v1.x + adv[2]);
      a_s[t][3] = lrelu02(v1.y + adv[3]);
      a_s[t][4] = lrelu02(v2.x + adv[4]);
      a_s[t][5] = lrelu02(v2.y + adv[5]);
    }
    __syncthreads();
    for (int hh = wave; hh < H; hh += 4) {
      float cm = -1e30f;
      for (int j = lane; j < ne; j += 64) cm = fmaxf(cm, a_s[j][hh]);
#pragma unroll
      for (int msk = 32; msk; msk >>= 1) cm = fmaxf(cm, __shfl_xor(cm, msk));
      float sm = 0.f;
      for (int j = lane; j < ne; j += 64) {
        float e = __expf(a_s[j][hh] - cm);   // chunk-local max
        a_s[j][hh] = e;
        sm += e;
      }
#pragma unroll
      for (int msk = 32; msk; msk >>= 1) sm += __shfl_xor(sm, msk);
      if (lane == 0) { nm_s[hh] = cm; sm_s[hh] = sm; }
    }
    __syncthreads();
    if (act) {
      float rsn[4];
#pragma unroll
      for (int r = 0; r < 4; ++r) {
        float cm = nm_s[hd[r]];
        float nm = fmaxf(m_r[r], cm);
        float rs_old = __expf(m_r[r] - nm);
        float rs_new = __expf(cm - nm);
        acc[r] *= rs_old;
        d_r[r] = d_r[r] * rs_old + sm_s[hd[r]] * rs_new;
        m_r[r] = nm;
        rsn[r] = rs_new;
      }
#pragma unroll 4
      for (int e = 0; e < ne; ++e) {
        const u8* hp = h + (size_t)src_s[e] * FP;
        int pk = *(const int*)(hp + c0);
        acc[0] += rsn[0] * a_s[e][hd[0]] * __builtin_amdgcn_cvt_f32_fp8(pk, 0);
        acc[1] += rsn[1] * a_s[e][hd[1]] * __builtin_amdgcn_cvt_f32_fp8(pk, 1);
        acc[2] += rsn[2] * a_s[e][hd[2]] * __builtin_amdgcn_cvt_f32_fp8(pk, 2);
        acc[3] += rsn[3] * a_s[e][hd[3]] * __builtin_amdgcn_cvt_f32_fp8(pk, 3);
      }
    }
  }
  __syncthreads();
  if (act) {
#pragma unroll
    for (int r = 0; r < 4; ++r) agg_s[c0 + r] = acc[r] / (d_r[r] + 1e-16f);
  }
  __syncthreads();
  if (t < C) {
    float s = 0.f;
#pragma unroll
    for (int hh = 0; hh < H; ++hh) s += agg_s[hh * C + t];
    size_t idx = (size_t)i * C + t;
    out[idx] += s * (1.f / 6.f) + bias[t];
  }
}

// ---------------- launch ----------------
extern "C" void kernel_launch(void* const* d_in, const int* in_sizes, int n_in,
                              void* d_out, int out_size, void* d_ws, size_t ws_size,
                              hipStream_t stream) {
  const float* x = (const float*)d_in[0];
  const int* ei = (const int*)d_in[1];
  const float* W1 = (const float*)d_in[2];
  const float* a_src1 = (const float*)d_in[3];
  const float* a_dst1 = (const float*)d_in[4];
  const float* b1 = (const float*)d_in[5];
  const float* lW1 = (const float*)d_in[6];
  const float* lb1 = (const float*)d_in[7];
  const float* W2 = (const float*)d_in[8];
  const float* a_src2 = (const float*)d_in[9];
  const float* a_dst2 = (const float*)d_in[10];
  const float* b2 = (const float*)d_in[11];
  const float* lW2 = (const float*)d_in[12];
  const float* lb2 = (const float*)d_in[13];
  const float* W3 = (const float*)d_in[14];
  const float* a_src3 = (const float*)d_in[15];
  const float* a_dst3 = (const float*)d_in[16];
  const float* b3 = (const float*)d_in[17];
  const float* lW3 = (const float*)d_in[18];
  const float* lb3 = (const float*)d_in[19];
  float* outp = (float*)d_out;

  char* ws = (char*)d_ws;
  size_t o = 0;
  auto alloc = [&](size_t bytes) { void* p = ws + o; o += (bytes + 255) & ~(size_t)255; return p; };
  u8* bufH8 = (u8*)alloc((size_t)MPAD * 1024);        // GAT-branch h (fp8)
  u16* bufX = (u16*)alloc((size_t)MPAD * 1024 * 2);   // layer output / GEMM A (bf16)
  u16* bufS = (u16*)alloc((size_t)NN * 1024 * 2);     // dense skip (bf16)
  u16* xb16 = (u16*)alloc((size_t)MPAD * 64 * 2);
  u16* wtc1 = (u16*)alloc((size_t)2048 * 64 * 2);
  u16* wtc2 = (u16*)alloc((size_t)2048 * 1024 * 2);
  u16* wtc3 = (u16*)alloc((size_t)896 * 1024 * 2);
  float* fb12 = (float*)alloc((size_t)4992 * 4);
  float* fb1 = fb12;
  float* fb2 = fb12 + 2048;
  float* fb3 = fb12 + 4096;
  float* as_ = (float*)alloc((size_t)NN * 6 * 4);
  float* ad_ = (float*)alloc((size_t)NN * 6 * 4);
  int* cnt = (int*)alloc((size_t)(3 * NN + 1) * 4);
  int* offs = cnt + NN;
  int* cursor = offs + NN + 1;
  int* csr_src = (int*)alloc((size_t)EN_ * 4);

  // ---- zero cnt|offs|cursor, then prep (incl. edge count), scan, fill ----
  hipMemsetAsync(cnt, 0, (size_t)(3 * NN + 1) * 4, stream);
  k_prep<<<PREP_BLOCKS, 256, 0, stream>>>(x, xb16, W1, lW1, W2, lW2, W3, lW3,
                                          wtc1, wtc2, wtc3, lb1, lb2, lb3, fb12,
                                          bufX, ei, cnt);
  k_scan<<<1, 1024, 0, stream>>>(cnt, offs);
  k_fill<<<(EN_ + 255) / 256, 256, 0, stream>>>(ei, offs, cursor, csr_src);

  // ---- Layer 1 (fused N=2048, Kpad=64) ----
  {
    k_gemm_fused<1><<<16 * 80, 256, 0, stream>>>(
        xb16, wtc1, fb1, bufH8, 1024, bufS, 1024, 1024, 1024, NN, 64, 16);
    k_scores256<<<10000, 256, 0, stream>>>(bufH8, a_src1, a_dst1, as_, ad_);
    k_agg_cat<<<NN, 256, 0, stream>>>(bufH8, as_, ad_, offs, csr_src, b1, bufS, bufX);
  }
  // ---- Layer 2 (fused N=2048, Kpad=1024) ----
  {
    k_gemm_fused<1><<<16 * 80, 256, 0, stream>>>(
        bufX, wtc2, fb2, bufH8, 1024, bufS, 1024, 1024, 1024, NN, 1024, 16);
    k_scores256<<<10000, 256, 0, stream>>>(bufH8, a_src2, a_dst2, as_, ad_);
    k_agg_cat<<<NN, 256, 0, stream>>>(bufH8, as_, ad_, offs, csr_src, b2, bufS, bufX);
  }
  // ---- Layer 3 (fused N=896) ----
  {
    k_gemm_fused<0><<<7 * 80, 256, 0, stream>>>(
        bufX, wtc3, fb3, bufH8, 768, outp, 121, 768, 121, NN, 1024, 7);
    k_scores<<<(NN * 6 + 3) / 4, 256, 0, stream>>>(bufH8, a_src3, a_dst3, as_, ad_, 6, 121, 768);
    k_agg_mean<<<NN, 256, 0, stream>>>(bufH8, as_, ad_, offs, csr_src, b3, outp);
  }
}